// Round 11
// baseline (342.789 us; speedup 1.0000x reference)
//
#include <hip/hip_runtime.h>
#include <hip/hip_bf16.h>

// ---------------- problem constants ----------------
#define HW    4096      // H*W
#define TT    8         // time steps

typedef _Float16 halfx8 __attribute__((ext_vector_type(8)));
typedef float    floatx4 __attribute__((ext_vector_type(4)));
typedef float    floatx2 __attribute__((ext_vector_type(2)));

__device__ inline float fast_exp2(float x) {
#if __has_builtin(__builtin_amdgcn_exp2f)
    return __builtin_amdgcn_exp2f(x);
#else
    return __builtin_exp2f(x);
#endif
}
__device__ inline float fast_rcp(float x) {
#if __has_builtin(__builtin_amdgcn_rcpf)
    return __builtin_amdgcn_rcpf(x);
#else
    return 1.0f / x;
#endif
}
__device__ inline floatx2 exp2x2(floatx2 x) {
    floatx2 r; r.x = fast_exp2(x.x); r.y = fast_exp2(x.y); return r;
}
__device__ inline floatx2 rcpx2(floatx2 x) {
    floatx2 r; r.x = fast_rcp(x.x); r.y = fast_rcp(x.y); return r;
}
__device__ inline floatx2 fsig2(floatx2 x) {          // sigmoid
    return rcpx2(exp2x2(x * -1.44269504088896f) + 1.0f);
}
__device__ inline floatx2 ftanh2(floatx2 x) {         // tanh
    floatx2 r = rcpx2(exp2x2(x * 2.88539008177793f) + 1.0f);
    return r * -2.0f + 1.0f;
}

union pack8 { _Float16 h[8]; uint4 u; };

// ---------------- single fused kernel: conv_in + LSTM + conv_out ----------------
// 640-thread blocks (10 waves) = 20-pixel tile x all 8 groups = 160 seqs,
// seq = g*20+px; wave wv owns seqs wv*16..+15 (may span group boundaries --
// gate tables are seq-agnostic so the MFMA mapping is unchanged).
// LDS cut to 70144 B by aliasing w_in/w_out staging into the h-state region
// (w_in before h zeroed; w_out after last h read) -> 2 blocks/CU = 20 waves/CU
// (vs 16 at r10's 80 KB). The kernel is latency-bound with all pipes <75%
// (r4->r7: waves 2->4 per SIMD gave -40%; VALU-mix changes r5/r8/r10 all
// neutral) -- resident waves are the only lever that has ever moved dur.
// t-loop is r7/r9-verbatim (asm clobber pins B-frags in LDS -> 52 VGPR; plain
// fsig2/ftanh2 -- batched-rcp was 2-for-2 neutral/negative).
// NO forced min-waves bound (r2/r3: arch/AGPR split + spills).
__global__ __launch_bounds__(640) void lstm_kernel(
    const float* __restrict__ hin,    // (B, 64, HW)
    const float* __restrict__ w_in,   // (64, 64)
    const float* __restrict__ b_in,   // (64,)
    const float* __restrict__ w_ih,   // (256, 1)
    const float* __restrict__ w_hh,   // (256, 64)
    const float* __restrict__ b_ih,   // (256,)
    const float* __restrict__ b_hh,   // (256,)
    const float* __restrict__ w_s,    // (1, 64)
    const float* __restrict__ b_s_p,  // (1,)
    const float* __restrict__ w_out,  // (64, 64)
    const float* __restrict__ b_out,  // (64,)
    float* __restrict__ out) {        // (B, 64, HW)
    __shared__ uint4 wfrag_lds[2176];                  // 34816 B: 32 w_hh + 2 w_s frags
    __shared__ floatx2 wxb_lds[256];                   // 2048 B: per-gate {w_x, bias}
    __shared__ __align__(16) float x_lds[1280];        // 5120 B: [t][seq160]
    __shared__ __align__(16) _Float16 h_lds[11520];    // 23040 B: 10 waves x 16 x 72;
                                                       //   aliased for w_in/w_out (stride 65)
    __shared__ __align__(16) float stile[1280];        // 5120 B: [c64][px20]; hin then s
    float* hreg = (float*)h_lds;                       // w staging alias

    int tid = threadIdx.x;
    int ptile = blockIdx.x;               // 0..204 (tail tile 204 has 16 px)
    int b     = blockIdx.y;
    int p0  = ptile * 20;
    int npx = (ptile == 204) ? 16 : 20;

    int lane = tid & 63;
    int wv   = tid >> 6;                  // 0..9
    int s    = lane & 15;
    int q    = lane >> 4;

    // ---- repack w_hh -> B-fragment-ordered f16 (frag fi=nb*2+kc, entry e=fi*64+l;
    //      lane l holds B[k=kc*32+(l>>4)*8+j][n=(l&15)] = w_hh[gate=(l&15)+16nb][hid=k])
    #pragma unroll
    for (int i = 0; i < 4; ++i) {
        int e = tid + 640 * i;
        if (e < 2048) {
            int l  = e & 63;
            int fi = e >> 6;
            int nb = fi >> 1, kc = fi & 1;
            int gate = (l & 15) + 16 * nb;
            int hid  = kc * 32 + (l >> 4) * 8;
            const floatx4* src = (const floatx4*)&w_hh[gate * 64 + hid];
            floatx4 v0 = src[0], v1 = src[1];
            pack8 p;
            p.h[0] = (_Float16)v0[0]; p.h[1] = (_Float16)v0[1];
            p.h[2] = (_Float16)v0[2]; p.h[3] = (_Float16)v0[3];
            p.h[4] = (_Float16)v1[0]; p.h[5] = (_Float16)v1[1];
            p.h[6] = (_Float16)v1[2]; p.h[7] = (_Float16)v1[3];
            wfrag_lds[e] = p.u;
        }
    }
    // s-projection fragments (entries 2048..2175): B[k][0] = w_s[k], other cols 0
    if (tid < 128) {
        int l = tid & 63, kc = tid >> 6;
        pack8 p;
        #pragma unroll
        for (int j = 0; j < 8; ++j) p.h[j] = (_Float16)0.0f;
        if ((l & 15) == 0) {
            #pragma unroll
            for (int j = 0; j < 8; ++j)
                p.h[j] = (_Float16)w_s[kc * 32 + (l >> 4) * 8 + j];
        }
        wfrag_lds[2048 + kc * 64 + l] = p.u;
    }
    // per-gate {w_x, bias}
    if (tid < 256) {
        floatx2 v; v.x = w_ih[tid]; v.y = b_ih[tid] + b_hh[tid];
        wxb_lds[tid] = v;
    }
    // stage w_in into h-region, rows stride 65 (bank-spread; r9: stride 64 = 8-way conflicts)
    #pragma unroll
    for (int i = 0; i < 7; ++i) {
        int idx = tid + 640 * i;
        if (idx < 4096) hreg[(idx >> 6) * 65 + (idx & 63)] = w_in[idx];
    }
    // stage hin tile (64 ch x 20 px); tail px padded with 0
    #pragma unroll
    for (int i = 0; i < 2; ++i) {
        int idx = tid + 640 * i;
        if (idx < 1280) {
            int cc = idx / 20, px = idx % 20;
            stile[idx] = (px < npx) ? hin[(b * 64 + cc) * HW + p0 + px] : 0.0f;
        }
    }
    __syncthreads();

    // ---- conv_in: thread -> (px, tq, g); computes x[t=tq] and x[t=tq+4] for seq g*20+px
    {
        int px   = tid % 20;
        int rest = tid / 20;              // 0..31
        int tq = rest & 3, g = rest >> 2;
        floatx2 xacc; xacc.x = b_in[g * 8 + tq]; xacc.y = b_in[g * 8 + tq + 4];
        #pragma unroll 8
        for (int cc = 0; cc < 64; ++cc) {
            float hv = stile[cc * 20 + px];
            floatx2 w;
            w.x = hreg[(g * 8 + tq) * 65 + cc];
            w.y = hreg[(g * 8 + tq + 4) * 65 + cc];
            xacc.x += w.x * hv;
            xacc.y += w.y * hv;
        }
        x_lds[tq * 160 + g * 20 + px]       = xacc.x;   // x[t][seq]
        x_lds[(tq + 4) * 160 + g * 20 + px] = xacc.y;
    }
    __syncthreads();   // conv_in reads of hreg (w_in) done before zeroing h
    // zero h state (5760 u32)
    #pragma unroll
    for (int i = 0; i < 9; ++i) {
        int idx = tid + 640 * i;
        if (idx < 5760) ((unsigned*)h_lds)[idx] = 0u;
    }
    __syncthreads();

    // per-lane s-write bases: seq wv*16+q*4+r -> stile[(g*8+t)*20+px] = gr*160 + t*20 + pxr
    int sb[4];
    #pragma unroll
    for (int r = 0; r < 4; ++r) {
        int sg = wv * 16 + q * 4 + r;
        int gr = sg / 20, pxr = sg % 20;
        sb[r] = gr * 160 + pxr;
    }

    _Float16* hrow = h_lds + wv * 16 * 72;
    float bs = b_s_p[0];

    float c_st[4][4];
    #pragma unroll
    for (int hb = 0; hb < 4; ++hb)
        #pragma unroll
        for (int r = 0; r < 4; ++r) c_st[hb][r] = 0.0f;

    for (int t = 0; t < TT; ++t) {
        // Hard memory barrier: forbids caching LDS B-frags in registers
        // across iterations (r7: this is what keeps VGPR at 52 -> high occupancy).
        asm volatile("" ::: "memory");

        halfx8 a0 = *(const halfx8*)(hrow + s * 72 + q * 8);        // k = 0..31
        halfx8 a1 = *(const halfx8*)(hrow + s * 72 + q * 8 + 32);   // k = 32..63

        // s_{t-1} = h_t @ w_s via MFMA (col 0 only); lanes s==0 hold seqs q*4+r
        if (t > 0) {
            halfx8 sb0 = *(const halfx8*)&wfrag_lds[2048 + lane];
            halfx8 sb1 = *(const halfx8*)&wfrag_lds[2112 + lane];
            floatx4 sa = {0.f, 0.f, 0.f, 0.f};
            sa = __builtin_amdgcn_mfma_f32_16x16x32_f16(a0, sb0, sa, 0, 0, 0);
            sa = __builtin_amdgcn_mfma_f32_16x16x32_f16(a1, sb1, sa, 0, 0, 0);
            if (s == 0) {
                int toff = (t - 1) * 20;
                stile[sb[0] + toff] = sa[0] + bs;
                stile[sb[1] + toff] = sa[1] + bs;
                stile[sb[2] + toff] = sa[2] + bs;
                stile[sb[3] + toff] = sa[3] + bs;
            }
        }

        floatx4 xv = *(const floatx4*)&x_lds[t * 160 + wv * 16 + q * 4];
        floatx2 xlo; xlo.x = xv[0]; xlo.y = xv[1];
        floatx2 xhi; xhi.x = xv[2]; xhi.y = xv[3];

        #pragma unroll
        for (int hb = 0; hb < 4; ++hb) {
            floatx4 acc[4];
            #pragma unroll
            for (int gi = 0; gi < 4; ++gi) {
                int nb = hb + 4 * gi;
                floatx2 wb = wxb_lds[s + 16 * nb];
                floatx2 lo = xlo * wb.x + wb.y;     // x*w_x + bias as C init (pk_fma)
                floatx2 hi = xhi * wb.x + wb.y;
                floatx4 a = {lo.x, lo.y, hi.x, hi.y};
                halfx8 b0 = *(const halfx8*)&wfrag_lds[(nb * 2 + 0) * 64 + lane];
                halfx8 b1 = *(const halfx8*)&wfrag_lds[(nb * 2 + 1) * 64 + lane];
                a = __builtin_amdgcn_mfma_f32_16x16x32_f16(a0, b0, a, 0, 0, 0);
                a = __builtin_amdgcn_mfma_f32_16x16x32_f16(a1, b1, a, 0, 0, 0);
                acc[gi] = a;
            }
            int s16 = s + 16 * hb;
            _Float16* wp = hrow + (q * 4) * 72 + s16;
            #pragma unroll
            for (int p = 0; p < 2; ++p) {
                int r0 = 2 * p;
                floatx2 iv; iv.x = acc[0][r0]; iv.y = acc[0][r0 + 1]; iv = fsig2(iv);
                floatx2 fv; fv.x = acc[1][r0]; fv.y = acc[1][r0 + 1]; fv = fsig2(fv);
                floatx2 gv; gv.x = acc[2][r0]; gv.y = acc[2][r0 + 1]; gv = ftanh2(gv);
                floatx2 ov; ov.x = acc[3][r0]; ov.y = acc[3][r0 + 1]; ov = fsig2(ov);
                floatx2 cp; cp.x = c_st[hb][r0]; cp.y = c_st[hb][r0 + 1];
                floatx2 c = fv * cp + iv * gv;
                c_st[hb][r0] = c.x; c_st[hb][r0 + 1] = c.y;
                floatx2 hn = ov * ftanh2(c);
                wp[(r0 + 0) * 72] = (_Float16)hn.x;   // state for t+1
                wp[(r0 + 1) * 72] = (_Float16)hn.y;
            }
        }
    }
    // final s_7 from h_8
    {
        asm volatile("" ::: "memory");
        halfx8 a0 = *(const halfx8*)(hrow + s * 72 + q * 8);
        halfx8 a1 = *(const halfx8*)(hrow + s * 72 + q * 8 + 32);
        halfx8 sb0 = *(const halfx8*)&wfrag_lds[2048 + lane];
        halfx8 sb1 = *(const halfx8*)&wfrag_lds[2112 + lane];
        floatx4 sa = {0.f, 0.f, 0.f, 0.f};
        sa = __builtin_amdgcn_mfma_f32_16x16x32_f16(a0, sb0, sa, 0, 0, 0);
        sa = __builtin_amdgcn_mfma_f32_16x16x32_f16(a1, sb1, sa, 0, 0, 0);
        if (s == 0) {
            stile[sb[0] + 140] = sa[0] + bs;
            stile[sb[1] + 140] = sa[1] + bs;
            stile[sb[2] + 140] = sa[2] + bs;
            stile[sb[3] + 140] = sa[3] + bs;
        }
    }
    __syncthreads();   // all h_lds reads + stile writes done

    // stage w_out into h-region (h state dead now), rows stride 65
    #pragma unroll
    for (int i = 0; i < 7; ++i) {
        int idx = tid + 640 * i;
        if (idx < 4096) hreg[(idx >> 6) * 65 + (idx & 63)] = w_out[idx];
    }
    __syncthreads();

    // ---- conv_out epilogue: out[b][o][p0+px] = sum_c w_out[o][c]*stile[c][px] + b_out[o]
    {
        int px = tid % 20;
        int o  = tid / 20;                 // 0..31 -> outputs o and o+32
        floatx2 acc; acc.x = b_out[o]; acc.y = b_out[o + 32];
        #pragma unroll 8
        for (int c = 0; c < 64; ++c) {
            float sv = stile[c * 20 + px];
            acc.x += hreg[o * 65 + c] * sv;
            acc.y += hreg[(o + 32) * 65 + c] * sv;
        }
        if (px < npx) {
            out[(b * 64 + o) * HW + p0 + px]      = acc.x;
            out[(b * 64 + o + 32) * HW + p0 + px] = acc.y;
        }
    }
}

extern "C" void kernel_launch(void* const* d_in, const int* in_sizes, int n_in,
                              void* d_out, int out_size, void* d_ws, size_t ws_size,
                              hipStream_t stream) {
    const float* h     = (const float*)d_in[0];
    const float* w_in  = (const float*)d_in[1];
    const float* b_in  = (const float*)d_in[2];
    const float* w_ih  = (const float*)d_in[3];
    const float* w_hh  = (const float*)d_in[4];
    const float* b_ih  = (const float*)d_in[5];
    const float* b_hh  = (const float*)d_in[6];
    const float* w_s   = (const float*)d_in[7];
    const float* b_s   = (const float*)d_in[8];
    const float* w_out = (const float*)d_in[9];
    const float* b_out = (const float*)d_in[10];
    float* out = (float*)d_out;
    (void)d_ws; (void)ws_size;

    // single fused kernel. 205 pixel-tiles (204x20px + 1x16px) x 8 batches,
    // 640 threads (10 waves) per block.
    lstm_kernel<<<dim3(205, 8), 640, 0, stream>>>(h, w_in, b_in, w_ih, w_hh,
                                                  b_ih, b_hh, w_s, b_s,
                                                  w_out, b_out, out);
}